// Round 1
// baseline (560.992 us; speedup 1.0000x reference)
//
#include <hip/hip_runtime.h>
#include <cmath>

typedef __bf16 bf16_t;
typedef __attribute__((ext_vector_type(8))) __bf16 bf16x8;
typedef __attribute__((ext_vector_type(4))) float f32x4;

#define SEQ   2048
#define NHEAD 16
#define DHEAD 64
#define NB    4
#define DIMSZ 1024
#define MROWS 8192

__device__ __forceinline__ void async_copy16(const void* g, void* lds) {
  __builtin_amdgcn_global_load_lds(
      (__attribute__((address_space(1))) void*)(g),
      (__attribute__((address_space(3))) void*)(lds), 16, 0, 0);
}

__device__ __forceinline__ f32x4 f32x4_zero() {
  f32x4 v; v[0] = 0.f; v[1] = 0.f; v[2] = 0.f; v[3] = 0.f; return v;
}

// ---------------- x fp32 -> bf16 ----------------
__global__ __launch_bounds__(256) void cvt_x(const float* __restrict__ x,
                                             bf16_t* __restrict__ xb) {
  size_t i = ((size_t)blockIdx.x * 256 + threadIdx.x) * 8;
  float4 f0 = *(const float4*)(x + i);
  float4 f1 = *(const float4*)(x + i + 4);
  bf16x8 o;
  o[0] = (__bf16)f0.x; o[1] = (__bf16)f0.y; o[2] = (__bf16)f0.z; o[3] = (__bf16)f0.w;
  o[4] = (__bf16)f1.x; o[5] = (__bf16)f1.y; o[6] = (__bf16)f1.z; o[7] = (__bf16)f1.w;
  *(bf16x8*)(xb + i) = o;
}

// ---------------- W [k][n] fp32 -> Wt [n][k] bf16 ----------------
__global__ __launch_bounds__(256) void transpose_w(
    const float* __restrict__ W0, const float* __restrict__ W1,
    const float* __restrict__ W2, const float* __restrict__ W3,
    bf16_t* __restrict__ T0, bf16_t* __restrict__ T1,
    bf16_t* __restrict__ T2, bf16_t* __restrict__ T3) {
  const float* W; bf16_t* T;
  switch (blockIdx.z) {
    case 0: W = W0; T = T0; break;
    case 1: W = W1; T = T1; break;
    case 2: W = W2; T = T2; break;
    default: W = W3; T = T3; break;
  }
  __shared__ float t[32][33];
  int tx = threadIdx.x, ty = threadIdx.y;
  int col = blockIdx.x * 32 + tx;
#pragma unroll
  for (int i = 0; i < 4; i++) {
    int row = blockIdx.y * 32 + ty + i * 8;
    t[ty + i * 8][tx] = W[row * DIMSZ + col];
  }
  __syncthreads();
#pragma unroll
  for (int i = 0; i < 4; i++) {
    int n = blockIdx.x * 32 + ty + i * 8;
    int k = blockIdx.y * 32 + tx;
    T[n * DIMSZ + k] = (bf16_t)t[tx][ty + i * 8];
  }
}

// ---------------- shared GEMM mainloop: C(128x128) = A(128xK) * Bt(128xK)^T --
// A row-major [m][k], Bt row-major [n][k], K = DIMSZ. XOR chunk-swizzled LDS
// (chunk = 16B of 8 bf16; slot = chunk ^ (row&7)) so global_load_lds's
// wave-uniform-base constraint and conflict-free ds_read_b128 coexist.
__device__ __forceinline__ void gemm_mainloop(
    const bf16_t* __restrict__ A, const bf16_t* __restrict__ Bt,
    int m0, int n0, f32x4 acc[4][4]) {
  __shared__ __attribute__((aligned(16))) bf16_t As[128 * 64];
  __shared__ __attribute__((aligned(16))) bf16_t Bs[128 * 64];
  const int tid = threadIdx.x;
  const int wid = tid >> 6, lane = tid & 63;
  const int quad = lane >> 4, l16 = lane & 15;
  const int wm = wid & 1, wn = wid >> 1;
  const int srow = lane >> 3;            // 0..7 within wave's 8-row group
  const int gchunk = (lane & 7) ^ srow;  // xor-swizzled source chunk
#pragma unroll
  for (int r = 0; r < 4; r++)
#pragma unroll
    for (int c = 0; c < 4; c++) acc[r][c] = f32x4_zero();

  for (int k0 = 0; k0 < DIMSZ; k0 += 64) {
#pragma unroll
    for (int c2 = 0; c2 < 4; c2++) {
      int row = c2 * 32 + wid * 8 + srow;
      async_copy16(A + (size_t)(m0 + row) * DIMSZ + k0 + gchunk * 8,
                   &As[(c2 * 32 + wid * 8) * 64]);
      async_copy16(Bt + (size_t)(n0 + row) * DIMSZ + k0 + gchunk * 8,
                   &Bs[(c2 * 32 + wid * 8) * 64]);
    }
    __syncthreads();
#pragma unroll
    for (int kk = 0; kk < 2; kk++) {
      bf16x8 af[4], bf[4];
#pragma unroll
      for (int r = 0; r < 4; r++) {
        int row = wm * 64 + r * 16 + l16;
        int slot = (kk * 4 + quad) ^ (row & 7);
        af[r] = *(const bf16x8*)(As + row * 64 + slot * 8);
      }
#pragma unroll
      for (int c = 0; c < 4; c++) {
        int row = wn * 64 + c * 16 + l16;
        int slot = (kk * 4 + quad) ^ (row & 7);
        bf[c] = *(const bf16x8*)(Bs + row * 64 + slot * 8);
      }
#pragma unroll
      for (int r = 0; r < 4; r++)
#pragma unroll
        for (int c = 0; c < 4; c++)
          acc[r][c] = __builtin_amdgcn_mfma_f32_16x16x32_bf16(af[r], bf[c],
                                                              acc[r][c], 0, 0, 0);
    }
    __syncthreads();
  }
}

// ---------------- QKV projection (grid.z selects q/k/v) ----------------
// epilogue writes bf16 head-major [b][h][n][d]
__global__ __launch_bounds__(256) void gemm_qkv(
    const bf16_t* __restrict__ A,
    const bf16_t* __restrict__ Wt0, const bf16_t* __restrict__ Wt1,
    const bf16_t* __restrict__ Wt2,
    const float* __restrict__ b0, const float* __restrict__ b1,
    const float* __restrict__ b2,
    bf16_t* __restrict__ o0, bf16_t* __restrict__ o1, bf16_t* __restrict__ o2) {
  const bf16_t* Bt; const float* bias; bf16_t* dst;
  if (blockIdx.z == 0)      { Bt = Wt0; bias = b0; dst = o0; }
  else if (blockIdx.z == 1) { Bt = Wt1; bias = b1; dst = o1; }
  else                      { Bt = Wt2; bias = b2; dst = o2; }
  const int m0 = blockIdx.x * 128, n0 = blockIdx.y * 128;
  f32x4 acc[4][4];
  gemm_mainloop(A, Bt, m0, n0, acc);
  const int lane = threadIdx.x & 63, wid = threadIdx.x >> 6;
  const int quad = lane >> 4, l16 = lane & 15;
  const int wm = wid & 1, wn = wid >> 1;
#pragma unroll
  for (int c = 0; c < 4; c++) {
    int col = n0 + wn * 64 + c * 16 + l16;
    float bv = bias[col];
    int hh = col >> 6, dd = col & 63;
#pragma unroll
    for (int r = 0; r < 4; r++)
#pragma unroll
      for (int rr = 0; rr < 4; rr++) {
        int row = m0 + wm * 64 + r * 16 + quad * 4 + rr;  // C/D: row=quad*4+reg
        int bb = row >> 11, nn = row & (SEQ - 1);
        dst[(((size_t)(bb * NHEAD + hh) * SEQ + nn) << 6) + dd] =
            (bf16_t)(acc[r][c][rr] + bv);
      }
  }
}

// ---------------- output projection -> fp32 d_out ----------------
__global__ __launch_bounds__(256) void gemm_out(
    const bf16_t* __restrict__ A, const bf16_t* __restrict__ Bt,
    const float* __restrict__ bias, float* __restrict__ dst) {
  const int m0 = blockIdx.x * 128, n0 = blockIdx.y * 128;
  f32x4 acc[4][4];
  gemm_mainloop(A, Bt, m0, n0, acc);
  const int lane = threadIdx.x & 63, wid = threadIdx.x >> 6;
  const int quad = lane >> 4, l16 = lane & 15;
  const int wm = wid & 1, wn = wid >> 1;
#pragma unroll
  for (int c = 0; c < 4; c++) {
    int col = n0 + wn * 64 + c * 16 + l16;
    float bv = bias[col];
#pragma unroll
    for (int r = 0; r < 4; r++)
#pragma unroll
      for (int rr = 0; rr < 4; rr++) {
        int row = m0 + wm * 64 + r * 16 + quad * 4 + rr;
        dst[(size_t)row * DIMSZ + col] = acc[r][c][rr] + bv;
      }
  }
}

// ---------------- flash attention, diagonal-masked, learnable temp ----------
// 1 WG = (b, h, 64 q-rows); wave w owns q rows [i0+16w, i0+16w+16)
__global__ __launch_bounds__(256) void attn_kernel(
    const bf16_t* __restrict__ qh, const bf16_t* __restrict__ kh,
    const bf16_t* __restrict__ vh, bf16_t* __restrict__ ao,
    const float* __restrict__ log_temp) {
  __shared__ __attribute__((aligned(16))) bf16_t Ks[64 * 64];      // [j][d] swizzled
  __shared__ __attribute__((aligned(16))) bf16_t Vt[64 * 64];      // [d][j] swizzled
  __shared__ __attribute__((aligned(16))) bf16_t Ps[4][16 * 72];   // per-wave P, pad 72
  const int tid = threadIdx.x;
  const int wid = tid >> 6, lane = tid & 63;
  const int quad = lane >> 4, l16 = lane & 15;
  const int i0 = blockIdx.x * 64;
  const int h = blockIdx.y, b = blockIdx.z;
  const size_t headoff = (size_t)(b * NHEAD + h) * SEQ * DHEAD;
  const bf16_t* Q = qh + headoff;
  const bf16_t* K = kh + headoff;
  const bf16_t* V = vh + headoff;
  const float scale = expf(log_temp[0]);
  const float NEG_INF = -__builtin_inff();

  bf16x8 qf[2];  // A-frag: Q[m=l16][k=quad*8+j], kk = 0/32
#pragma unroll
  for (int kk = 0; kk < 2; kk++)
    qf[kk] = *(const bf16x8*)(Q + (size_t)(i0 + wid * 16 + l16) * DHEAD +
                              kk * 32 + quad * 8);
  float m_i[4], l_i[4];
  f32x4 oacc[4];
#pragma unroll
  for (int rr = 0; rr < 4; rr++) { m_i[rr] = NEG_INF; l_i[rr] = 0.f; }
#pragma unroll
  for (int c = 0; c < 4; c++) oacc[c] = f32x4_zero();

  const int srow = lane >> 3;
  const int gchunk = (lane & 7) ^ srow;
  const int qrow0 = i0 + wid * 16 + quad * 4;

  for (int j0 = 0; j0 < SEQ; j0 += 64) {
    // stage K tile (async, xor-swizzled)
#pragma unroll
    for (int c2 = 0; c2 < 2; c2++) {
      int row = c2 * 32 + wid * 8 + srow;
      async_copy16(K + (size_t)(j0 + row) * DHEAD + gchunk * 8,
                   &Ks[(c2 * 32 + wid * 8) * 64]);
    }
    // stage V transposed: Vt[d][j], swizzled chunk = (j>>3)^(d&7)
#pragma unroll
    for (int it = 0; it < 2; it++) {
      int krow = it * 32 + (tid >> 3);
      int d0 = (tid & 7) * 8;
      bf16x8 vv = *(const bf16x8*)(V + (size_t)(j0 + krow) * DHEAD + d0);
#pragma unroll
      for (int e = 0; e < 8; e++) {
        int d = d0 + e;
        int slot = (krow >> 3) ^ (d & 7);
        Vt[d * 64 + slot * 8 + (krow & 7)] = vv[e];
      }
    }
    __syncthreads();

    // S(16x64) = Q Kt ; C-layout: row=quad*4+rr, col=c*16+l16
    float p[4][4];
#pragma unroll
    for (int c = 0; c < 4; c++) {
      f32x4 s = f32x4_zero();
#pragma unroll
      for (int kk = 0; kk < 2; kk++) {
        int row = c * 16 + l16;
        int slot = (kk * 4 + quad) ^ (row & 7);
        bf16x8 kf = *(const bf16x8*)(Ks + row * 64 + slot * 8);
        s = __builtin_amdgcn_mfma_f32_16x16x32_bf16(qf[kk], kf, s, 0, 0, 0);
      }
#pragma unroll
      for (int rr = 0; rr < 4; rr++) p[c][rr] = s[rr];
    }

    // online softmax per q-row (16-lane butterfly within quad group)
#pragma unroll
    for (int rr = 0; rr < 4; rr++) {
      float mx = NEG_INF;
#pragma unroll
      for (int c = 0; c < 4; c++) {
        float sv = p[c][rr] * scale;
        if (qrow0 + rr == j0 + c * 16 + l16) sv = NEG_INF;  // diagonal mask
        p[c][rr] = sv;
        mx = fmaxf(mx, sv);
      }
#pragma unroll
      for (int off = 1; off < 16; off <<= 1) mx = fmaxf(mx, __shfl_xor(mx, off));
      float mn = fmaxf(m_i[rr], mx);
      float alpha = expf(m_i[rr] - mn);   // first tile: exp(-inf) = 0
      float s_ = 0.f;
#pragma unroll
      for (int c = 0; c < 4; c++) {
        float pv = expf(p[c][rr] - mn);
        p[c][rr] = pv;
        s_ += pv;
      }
#pragma unroll
      for (int off = 1; off < 16; off <<= 1) s_ += __shfl_xor(s_, off);
      l_i[rr] = l_i[rr] * alpha + s_;
      m_i[rr] = mn;
#pragma unroll
      for (int c = 0; c < 4; c++) oacc[c][rr] *= alpha;
    }

    // P: C-layout -> A-layout via per-wave LDS (same-wave DS ops are in-order)
    bf16_t* Pw = Ps[wid];
#pragma unroll
    for (int c = 0; c < 4; c++)
#pragma unroll
      for (int rr = 0; rr < 4; rr++)
        Pw[(quad * 4 + rr) * 72 + c * 16 + l16] = (bf16_t)p[c][rr];

    // O(16x64) += P(16x64) @ V(64x64)
#pragma unroll
    for (int c = 0; c < 4; c++)
#pragma unroll
      for (int jj = 0; jj < 2; jj++) {
        bf16x8 pa = *(const bf16x8*)(Pw + l16 * 72 + jj * 32 + quad * 8);
        int vrow = c * 16 + l16;
        int slot = (jj * 4 + quad) ^ (vrow & 7);
        bf16x8 vb = *(const bf16x8*)(Vt + vrow * 64 + slot * 8);
        oacc[c] = __builtin_amdgcn_mfma_f32_16x16x32_bf16(pa, vb, oacc[c], 0, 0, 0);
      }
    __syncthreads();
  }

  // epilogue: O /= l, write bf16 [b][n][h*64+d]
#pragma unroll
  for (int rr = 0; rr < 4; rr++) {
    float inv = 1.f / l_i[rr];
    int row = i0 + wid * 16 + quad * 4 + rr;
#pragma unroll
    for (int c = 0; c < 4; c++) {
      int col = h * DHEAD + c * 16 + l16;
      ao[(size_t)(b * SEQ + row) * DIMSZ + col] = (bf16_t)(oacc[c][rr] * inv);
    }
  }
}

extern "C" void kernel_launch(void* const* d_in, const int* in_sizes, int n_in,
                              void* d_out, int out_size, void* d_ws, size_t ws_size,
                              hipStream_t stream) {
  const float* x  = (const float*)d_in[0];
  const float* Wq = (const float*)d_in[1];
  const float* bq = (const float*)d_in[2];
  const float* Wk = (const float*)d_in[3];
  const float* bk = (const float*)d_in[4];
  const float* Wv = (const float*)d_in[5];
  const float* bv = (const float*)d_in[6];
  const float* Wo = (const float*)d_in[7];
  const float* bo = (const float*)d_in[8];
  const float* lt = (const float*)d_in[9];

  // workspace layout (bf16 elements); ao aliases xb (xb dead after QKV GEMMs)
  bf16_t* xb  = (bf16_t*)d_ws;                         // 8192*1024
  bf16_t* wtq = xb  + (size_t)MROWS * DIMSZ;           // 1024*1024 each
  bf16_t* wtk = wtq + (size_t)DIMSZ * DIMSZ;
  bf16_t* wtv = wtk + (size_t)DIMSZ * DIMSZ;
  bf16_t* wto = wtv + (size_t)DIMSZ * DIMSZ;
  bf16_t* qh  = wto + (size_t)DIMSZ * DIMSZ;           // 8192*1024 each
  bf16_t* kh  = qh  + (size_t)MROWS * DIMSZ;
  bf16_t* vh  = kh  + (size_t)MROWS * DIMSZ;
  bf16_t* ao  = xb;                                    // alias

  cvt_x<<<dim3(MROWS * DIMSZ / 2048), dim3(256), 0, stream>>>(x, xb);
  transpose_w<<<dim3(32, 32, 4), dim3(32, 8), 0, stream>>>(
      Wq, Wk, Wv, Wo, wtq, wtk, wtv, wto);
  gemm_qkv<<<dim3(64, 8, 3), dim3(256), 0, stream>>>(
      xb, wtq, wtk, wtv, bq, bk, bv, qh, kh, vh);
  attn_kernel<<<dim3(32, NHEAD, NB), dim3(256), 0, stream>>>(qh, kh, vh, ao, lt);
  gemm_out<<<dim3(64, 8), dim3(256), 0, stream>>>(ao, wto, bo, (float*)d_out);
}

// Round 2
// 291.735 us; speedup vs baseline: 1.9230x; 1.9230x over previous
//
#include <hip/hip_runtime.h>
#include <cmath>

typedef __bf16 bf16_t;
typedef __attribute__((ext_vector_type(8))) __bf16 bf16x8;
typedef __attribute__((ext_vector_type(4))) __bf16 bf16x4;
typedef __attribute__((ext_vector_type(4))) float f32x4;

#define SEQ   2048
#define NHEAD 16
#define DHEAD 64
#define NB    4
#define DIMSZ 1024
#define MROWS 8192

__device__ __forceinline__ void async_copy16(const void* g, void* lds) {
  __builtin_amdgcn_global_load_lds(
      (__attribute__((address_space(1))) void*)(g),
      (__attribute__((address_space(3))) void*)(lds), 16, 0, 0);
}

__device__ __forceinline__ f32x4 f32x4_zero() {
  f32x4 v; v[0] = 0.f; v[1] = 0.f; v[2] = 0.f; v[3] = 0.f; return v;
}

// ---------------- x fp32 -> bf16 ----------------
__global__ __launch_bounds__(256) void cvt_x(const float* __restrict__ x,
                                             bf16_t* __restrict__ xb) {
  size_t i = ((size_t)blockIdx.x * 256 + threadIdx.x) * 8;
  float4 f0 = *(const float4*)(x + i);
  float4 f1 = *(const float4*)(x + i + 4);
  bf16x8 o;
  o[0] = (__bf16)f0.x; o[1] = (__bf16)f0.y; o[2] = (__bf16)f0.z; o[3] = (__bf16)f0.w;
  o[4] = (__bf16)f1.x; o[5] = (__bf16)f1.y; o[6] = (__bf16)f1.z; o[7] = (__bf16)f1.w;
  *(bf16x8*)(xb + i) = o;
}

// ---------------- W [k][n] fp32 -> Wt [n][k] bf16 ----------------
__global__ __launch_bounds__(256) void transpose_w(
    const float* __restrict__ W0, const float* __restrict__ W1,
    const float* __restrict__ W2, const float* __restrict__ W3,
    bf16_t* __restrict__ T0, bf16_t* __restrict__ T1,
    bf16_t* __restrict__ T2, bf16_t* __restrict__ T3) {
  const float* W; bf16_t* T;
  switch (blockIdx.z) {
    case 0: W = W0; T = T0; break;
    case 1: W = W1; T = T1; break;
    case 2: W = W2; T = T2; break;
    default: W = W3; T = T3; break;
  }
  __shared__ float t[32][33];
  int tx = threadIdx.x, ty = threadIdx.y;
  int col = blockIdx.x * 32 + tx;
#pragma unroll
  for (int i = 0; i < 4; i++) {
    int row = blockIdx.y * 32 + ty + i * 8;
    t[ty + i * 8][tx] = W[row * DIMSZ + col];
  }
  __syncthreads();
#pragma unroll
  for (int i = 0; i < 4; i++) {
    int n = blockIdx.x * 32 + ty + i * 8;
    int k = blockIdx.y * 32 + tx;
    T[n * DIMSZ + k] = (bf16_t)t[tx][ty + i * 8];
  }
}

// ---------------- shared GEMM mainloop: C(128x128) = A(128xK) * Bt(128xK)^T --
__device__ __forceinline__ void gemm_mainloop(
    const bf16_t* __restrict__ A, const bf16_t* __restrict__ Bt,
    int m0, int n0, f32x4 acc[4][4]) {
  __shared__ __attribute__((aligned(16))) bf16_t As[128 * 64];
  __shared__ __attribute__((aligned(16))) bf16_t Bs[128 * 64];
  const int tid = threadIdx.x;
  const int wid = tid >> 6, lane = tid & 63;
  const int quad = lane >> 4, l16 = lane & 15;
  const int wm = wid & 1, wn = wid >> 1;
  const int srow = lane >> 3;
  const int gchunk = (lane & 7) ^ srow;
#pragma unroll
  for (int r = 0; r < 4; r++)
#pragma unroll
    for (int c = 0; c < 4; c++) acc[r][c] = f32x4_zero();

  for (int k0 = 0; k0 < DIMSZ; k0 += 64) {
#pragma unroll
    for (int c2 = 0; c2 < 4; c2++) {
      int row = c2 * 32 + wid * 8 + srow;
      async_copy16(A + (size_t)(m0 + row) * DIMSZ + k0 + gchunk * 8,
                   &As[(c2 * 32 + wid * 8) * 64]);
      async_copy16(Bt + (size_t)(n0 + row) * DIMSZ + k0 + gchunk * 8,
                   &Bs[(c2 * 32 + wid * 8) * 64]);
    }
    __syncthreads();
#pragma unroll
    for (int kk = 0; kk < 2; kk++) {
      bf16x8 af[4], bf[4];
#pragma unroll
      for (int r = 0; r < 4; r++) {
        int row = wm * 64 + r * 16 + l16;
        int slot = (kk * 4 + quad) ^ (row & 7);
        af[r] = *(const bf16x8*)(As + row * 64 + slot * 8);
      }
#pragma unroll
      for (int c = 0; c < 4; c++) {
        int row = wn * 64 + c * 16 + l16;
        int slot = (kk * 4 + quad) ^ (row & 7);
        bf[c] = *(const bf16x8*)(Bs + row * 64 + slot * 8);
      }
#pragma unroll
      for (int r = 0; r < 4; r++)
#pragma unroll
        for (int c = 0; c < 4; c++)
          acc[r][c] = __builtin_amdgcn_mfma_f32_16x16x32_bf16(af[r], bf[c],
                                                              acc[r][c], 0, 0, 0);
    }
    __syncthreads();
  }
}

// ---------------- QKV projection (grid.z selects q/k/v) ----------------
// q,k: bf16 head-major [b][h][n][d]; v: TRANSPOSED [b][h][d][n]
__global__ __launch_bounds__(256) void gemm_qkv(
    const bf16_t* __restrict__ A,
    const bf16_t* __restrict__ Wt0, const bf16_t* __restrict__ Wt1,
    const bf16_t* __restrict__ Wt2,
    const float* __restrict__ b0, const float* __restrict__ b1,
    const float* __restrict__ b2,
    bf16_t* __restrict__ o0, bf16_t* __restrict__ o1, bf16_t* __restrict__ o2) {
  const bf16_t* Bt; const float* bias; bf16_t* dst;
  if (blockIdx.z == 0)      { Bt = Wt0; bias = b0; dst = o0; }
  else if (blockIdx.z == 1) { Bt = Wt1; bias = b1; dst = o1; }
  else                      { Bt = Wt2; bias = b2; dst = o2; }
  const int m0 = blockIdx.x * 128, n0 = blockIdx.y * 128;
  f32x4 acc[4][4];
  gemm_mainloop(A, Bt, m0, n0, acc);
  const int lane = threadIdx.x & 63, wid = threadIdx.x >> 6;
  const int quad = lane >> 4, l16 = lane & 15;
  const int wm = wid & 1, wn = wid >> 1;
  if (blockIdx.z == 2) {
    // V^T epilogue: [b][h][d][n], vectorized 8B stores (4 consecutive n)
#pragma unroll
    for (int c = 0; c < 4; c++) {
      int col = n0 + wn * 64 + c * 16 + l16;
      float bv = bias[col];
      int hh = col >> 6, dd = col & 63;
#pragma unroll
      for (int r = 0; r < 4; r++) {
        int row = m0 + wm * 64 + r * 16 + quad * 4;
        int bb = row >> 11, nn = row & (SEQ - 1);
        bf16x4 pk;
#pragma unroll
        for (int rr = 0; rr < 4; rr++) pk[rr] = (__bf16)(acc[r][c][rr] + bv);
        *(bf16x4*)(dst + ((size_t)(bb * NHEAD + hh) * DHEAD + dd) * SEQ + nn) = pk;
      }
    }
  } else {
#pragma unroll
    for (int c = 0; c < 4; c++) {
      int col = n0 + wn * 64 + c * 16 + l16;
      float bv = bias[col];
      int hh = col >> 6, dd = col & 63;
#pragma unroll
      for (int r = 0; r < 4; r++)
#pragma unroll
        for (int rr = 0; rr < 4; rr++) {
          int row = m0 + wm * 64 + r * 16 + quad * 4 + rr;
          int bb = row >> 11, nn = row & (SEQ - 1);
          dst[(((size_t)(bb * NHEAD + hh) * SEQ + nn) << 6) + dd] =
              (bf16_t)(acc[r][c][rr] + bv);
        }
    }
  }
}

// ---------------- output projection -> fp32 d_out ----------------
__global__ __launch_bounds__(256) void gemm_out(
    const bf16_t* __restrict__ A, const bf16_t* __restrict__ Bt,
    const float* __restrict__ bias, float* __restrict__ dst) {
  const int m0 = blockIdx.x * 128, n0 = blockIdx.y * 128;
  f32x4 acc[4][4];
  gemm_mainloop(A, Bt, m0, n0, acc);
  const int lane = threadIdx.x & 63, wid = threadIdx.x >> 6;
  const int quad = lane >> 4, l16 = lane & 15;
  const int wm = wid & 1, wn = wid >> 1;
#pragma unroll
  for (int c = 0; c < 4; c++) {
    int col = n0 + wn * 64 + c * 16 + l16;
    float bv = bias[col];
#pragma unroll
    for (int r = 0; r < 4; r++)
#pragma unroll
      for (int rr = 0; rr < 4; rr++) {
        int row = m0 + wm * 64 + r * 16 + quad * 4 + rr;
        dst[(size_t)row * DIMSZ + col] = acc[r][c][rr] + bv;
      }
  }
}

// ---------------- flash attention v2 ----------------
// S^T = K*Q^T (lane owns one q-row => in-lane softmax), fixed-max exp,
// V staged pre-transposed from global, swizzled vectorized P round-trip.
// 1 WG = (b, h, 128 q-rows); wave w owns q rows [i0+32w, i0+32w+32)
__global__ __launch_bounds__(256, 4) void attn_kernel(
    const bf16_t* __restrict__ qh, const bf16_t* __restrict__ kh,
    const bf16_t* __restrict__ vt, bf16_t* __restrict__ ao,
    const float* __restrict__ log_temp) {
  __shared__ __attribute__((aligned(16))) bf16_t Ks[64 * 64];      // [j][d] swizzled
  __shared__ __attribute__((aligned(16))) bf16_t Vs[64 * 64];      // [d][j] swizzled
  __shared__ __attribute__((aligned(16))) bf16_t Ps[4][32 * 64];   // per-wave P[i][j] swizzled
  const int tid = threadIdx.x;
  const int wid = tid >> 6, lane = tid & 63;
  const int quad = lane >> 4, l16 = lane & 15;
  const int i0 = blockIdx.x * 128;
  const int h = blockIdx.y, b = blockIdx.z;
  const size_t ho = (size_t)(b * NHEAD + h) * SEQ * DHEAD;
  const bf16_t* Q = qh + ho;
  // fixed-max softmax: p = exp2(s * (temp*log2e) - M*log2e), M = 16
  const float ascale = expf(log_temp[0]) * 1.44269504f;
  const float bshift = 16.0f * 1.44269504f;

  const int irow = i0 + wid * 32;  // wave's first q row
  bf16x8 qf[2][2];
#pragma unroll
  for (int g = 0; g < 2; g++)
#pragma unroll
    for (int jj = 0; jj < 2; jj++)
      qf[g][jj] = *(const bf16x8*)(Q + (size_t)(irow + g * 16 + l16) * DHEAD +
                                   jj * 32 + quad * 8);

  f32x4 oacc[4][2];
#pragma unroll
  for (int c = 0; c < 4; c++)
#pragma unroll
    for (int g = 0; g < 2; g++) oacc[c][g] = f32x4_zero();
  float lsum[2] = {0.f, 0.f};

  const int srow = lane >> 3;
  const int gch = (lane & 7) ^ srow;
  const bf16_t* kg = kh + ho + (size_t)(wid * 8 + srow) * DHEAD + gch * 8;
  const bf16_t* vg = vt + ho + (size_t)(wid * 8 + srow) * SEQ + gch * 8;
  bf16_t* ksd = &Ks[wid * 8 * 64];
  bf16_t* vsd = &Vs[wid * 8 * 64];
  bf16_t* Pw = Ps[wid];
  const int jdiag = i0 + (wid >> 1) * 64;  // j-tile containing this wave's diag
  const int x7 = l16 & 7;

  for (int j0 = 0; j0 < SEQ; j0 += 64) {
    async_copy16(kg, ksd);
    async_copy16(kg + 32 * DHEAD, ksd + 32 * 64);
    async_copy16(vg, vsd);
    async_copy16(vg + 32 * SEQ, vsd + 32 * 64);
    kg += 64 * DHEAD;
    vg += 64;
    __syncthreads();

    // S^T(64x32) = K * Q^T : D[j][i], row j = c*16+quad*4+rr, col i = g*16+l16
    f32x4 st[4][2];
#pragma unroll
    for (int c = 0; c < 4; c++) {
      const int krow = c * 16 + l16;
      bf16x8 kf0 = *(const bf16x8*)(Ks + krow * 64 + ((0 + quad) ^ x7) * 8);
      bf16x8 kf1 = *(const bf16x8*)(Ks + krow * 64 + ((4 + quad) ^ x7) * 8);
#pragma unroll
      for (int g = 0; g < 2; g++) {
        f32x4 s = f32x4_zero();
        s = __builtin_amdgcn_mfma_f32_16x16x32_bf16(kf0, qf[g][0], s, 0, 0, 0);
        s = __builtin_amdgcn_mfma_f32_16x16x32_bf16(kf1, qf[g][1], s, 0, 0, 0);
        st[c][g] = s;
      }
    }

    // in-lane softmax (fixed max) + bf16 pack + vectorized P write
    const bool isdiag = (j0 == jdiag);
#pragma unroll
    for (int g = 0; g < 2; g++) {
      float ls = 0.f;
      const int ig = irow + g * 16 + l16;
#pragma unroll
      for (int c = 0; c < 4; c++) {
        bf16x4 pk;
#pragma unroll
        for (int rr = 0; rr < 4; rr++) {
          float e = __builtin_amdgcn_exp2f(fmaf(st[c][g][rr], ascale, -bshift));
          if (isdiag && (j0 + c * 16 + quad * 4 + rr == ig)) e = 0.f;
          ls += e;
          pk[rr] = (__bf16)e;
        }
        int slot = (2 * c + (quad >> 1)) ^ x7;
        *(bf16x4*)(Pw + (g * 16 + l16) * 64 + slot * 8 + (quad & 1) * 4) = pk;
      }
      lsum[g] += ls;
    }

    // O(32x64) += P(32x64) @ V^T(64x64)^T : per g, A=P rows, B=V^T rows(d)
    bf16x8 pa[2][2];
#pragma unroll
    for (int g = 0; g < 2; g++) {
      pa[g][0] = *(const bf16x8*)(Pw + (g * 16 + l16) * 64 + ((0 + quad) ^ x7) * 8);
      pa[g][1] = *(const bf16x8*)(Pw + (g * 16 + l16) * 64 + ((4 + quad) ^ x7) * 8);
    }
#pragma unroll
    for (int c = 0; c < 4; c++) {
      const int vrow = c * 16 + l16;
      bf16x8 vb0 = *(const bf16x8*)(Vs + vrow * 64 + ((0 + quad) ^ x7) * 8);
      bf16x8 vb1 = *(const bf16x8*)(Vs + vrow * 64 + ((4 + quad) ^ x7) * 8);
#pragma unroll
      for (int g = 0; g < 2; g++) {
        oacc[c][g] = __builtin_amdgcn_mfma_f32_16x16x32_bf16(pa[g][0], vb0,
                                                             oacc[c][g], 0, 0, 0);
        oacc[c][g] = __builtin_amdgcn_mfma_f32_16x16x32_bf16(pa[g][1], vb1,
                                                             oacc[c][g], 0, 0, 0);
      }
    }
    __syncthreads();
  }

  // final l reduction (across the 4 quads holding the same q-row)
#pragma unroll
  for (int g = 0; g < 2; g++) {
    lsum[g] += __shfl_xor(lsum[g], 16);
    lsum[g] += __shfl_xor(lsum[g], 32);
  }
  // epilogue: O /= l, write bf16 [b][n][h*64+d]
#pragma unroll
  for (int g = 0; g < 2; g++)
#pragma unroll
    for (int rr = 0; rr < 4; rr++) {
      float lr = __shfl(lsum[g], (lane & 48) | (quad * 4 + rr));
      float inv = 1.f / lr;
      int row = irow + g * 16 + quad * 4 + rr;
#pragma unroll
      for (int c = 0; c < 4; c++) {
        ao[(size_t)(b * SEQ + row) * DIMSZ + h * DHEAD + c * 16 + l16] =
            (bf16_t)(oacc[c][g][rr] * inv);
      }
    }
}

extern "C" void kernel_launch(void* const* d_in, const int* in_sizes, int n_in,
                              void* d_out, int out_size, void* d_ws, size_t ws_size,
                              hipStream_t stream) {
  const float* x  = (const float*)d_in[0];
  const float* Wq = (const float*)d_in[1];
  const float* bq = (const float*)d_in[2];
  const float* Wk = (const float*)d_in[3];
  const float* bk = (const float*)d_in[4];
  const float* Wv = (const float*)d_in[5];
  const float* bv = (const float*)d_in[6];
  const float* Wo = (const float*)d_in[7];
  const float* bo = (const float*)d_in[8];
  const float* lt = (const float*)d_in[9];

  bf16_t* xb  = (bf16_t*)d_ws;                         // 8192*1024
  bf16_t* wtq = xb  + (size_t)MROWS * DIMSZ;           // 1024*1024 each
  bf16_t* wtk = wtq + (size_t)DIMSZ * DIMSZ;
  bf16_t* wtv = wtk + (size_t)DIMSZ * DIMSZ;
  bf16_t* wto = wtv + (size_t)DIMSZ * DIMSZ;
  bf16_t* qh  = wto + (size_t)DIMSZ * DIMSZ;           // 8192*1024 each
  bf16_t* kh  = qh  + (size_t)MROWS * DIMSZ;
  bf16_t* vh  = kh  + (size_t)MROWS * DIMSZ;           // holds V^T [b][h][d][n]
  bf16_t* ao  = xb;                                    // alias (xb dead after QKV)

  cvt_x<<<dim3(MROWS * DIMSZ / 2048), dim3(256), 0, stream>>>(x, xb);
  transpose_w<<<dim3(32, 32, 4), dim3(32, 8), 0, stream>>>(
      Wq, Wk, Wv, Wo, wtq, wtk, wtv, wto);
  gemm_qkv<<<dim3(64, 8, 3), dim3(256), 0, stream>>>(
      xb, wtq, wtk, wtv, bq, bk, bv, qh, kh, vh);
  attn_kernel<<<dim3(16, NHEAD, NB), dim3(256), 0, stream>>>(qh, kh, vh, ao, lt);
  gemm_out<<<dim3(64, 8), dim3(256), 0, stream>>>(ao, wto, bo, (float*)d_out);
}

// Round 3
// 279.567 us; speedup vs baseline: 2.0067x; 1.0435x over previous
//
#include <hip/hip_runtime.h>
#include <cmath>

typedef __bf16 bf16_t;
typedef __attribute__((ext_vector_type(8))) __bf16 bf16x8;
typedef __attribute__((ext_vector_type(4))) __bf16 bf16x4;
typedef __attribute__((ext_vector_type(4))) float f32x4;

#define SEQ   2048
#define NHEAD 16
#define DHEAD 64
#define NB    4
#define DIMSZ 1024
#define MROWS 8192

__device__ __forceinline__ void async_copy16(const void* g, void* lds) {
  __builtin_amdgcn_global_load_lds(
      (__attribute__((address_space(1))) void*)(g),
      (__attribute__((address_space(3))) void*)(lds), 16, 0, 0);
}

__device__ __forceinline__ f32x4 f32x4_zero() {
  f32x4 v; v[0] = 0.f; v[1] = 0.f; v[2] = 0.f; v[3] = 0.f; return v;
}

// ---------------- x fp32 -> bf16 ----------------
__global__ __launch_bounds__(256) void cvt_x(const float* __restrict__ x,
                                             bf16_t* __restrict__ xb) {
  size_t i = ((size_t)blockIdx.x * 256 + threadIdx.x) * 8;
  float4 f0 = *(const float4*)(x + i);
  float4 f1 = *(const float4*)(x + i + 4);
  bf16x8 o;
  o[0] = (__bf16)f0.x; o[1] = (__bf16)f0.y; o[2] = (__bf16)f0.z; o[3] = (__bf16)f0.w;
  o[4] = (__bf16)f1.x; o[5] = (__bf16)f1.y; o[6] = (__bf16)f1.z; o[7] = (__bf16)f1.w;
  *(bf16x8*)(xb + i) = o;
}

// ---------------- W [k][n] fp32 -> Wt [n][k] bf16 ----------------
__global__ __launch_bounds__(256) void transpose_w(
    const float* __restrict__ W0, const float* __restrict__ W1,
    const float* __restrict__ W2, const float* __restrict__ W3,
    bf16_t* __restrict__ T0, bf16_t* __restrict__ T1,
    bf16_t* __restrict__ T2, bf16_t* __restrict__ T3) {
  const float* W; bf16_t* T;
  switch (blockIdx.z) {
    case 0: W = W0; T = T0; break;
    case 1: W = W1; T = T1; break;
    case 2: W = W2; T = T2; break;
    default: W = W3; T = T3; break;
  }
  __shared__ float t[32][33];
  int tx = threadIdx.x, ty = threadIdx.y;
  int col = blockIdx.x * 32 + tx;
#pragma unroll
  for (int i = 0; i < 4; i++) {
    int row = blockIdx.y * 32 + ty + i * 8;
    t[ty + i * 8][tx] = W[row * DIMSZ + col];
  }
  __syncthreads();
#pragma unroll
  for (int i = 0; i < 4; i++) {
    int n = blockIdx.x * 32 + ty + i * 8;
    int k = blockIdx.y * 32 + tx;
    T[n * DIMSZ + k] = (bf16_t)t[tx][ty + i * 8];
  }
}

// ---------------- shared GEMM mainloop: C(128x128) = A(128xK) * Bt(128xK)^T --
// Double-buffered, prefetch-after-barrier: copies for iter it+1 are in flight
// during iter it's compute, so the vmcnt(0) drain at the next barrier is cheap.
__device__ __forceinline__ void gemm_mainloop(
    const bf16_t* __restrict__ A, const bf16_t* __restrict__ Bt,
    int m0, int n0, f32x4 acc[4][4]) {
  __shared__ __attribute__((aligned(16))) bf16_t As[2][128 * 64];
  __shared__ __attribute__((aligned(16))) bf16_t Bs[2][128 * 64];
  const int tid = threadIdx.x;
  const int wid = tid >> 6, lane = tid & 63;
  const int quad = lane >> 4, l16 = lane & 15;
  const int wm = wid & 1, wn = wid >> 1;
  const int srow = lane >> 3;
  const int gchunk = (lane & 7) ^ srow;
#pragma unroll
  for (int r = 0; r < 4; r++)
#pragma unroll
    for (int c = 0; c < 4; c++) acc[r][c] = f32x4_zero();

  const bf16_t* ag = A + (size_t)(m0 + wid * 8 + srow) * DIMSZ + gchunk * 8;
  const bf16_t* bg = Bt + (size_t)(n0 + wid * 8 + srow) * DIMSZ + gchunk * 8;

  auto stage = [&](int k0, int buf) {
#pragma unroll
    for (int c2 = 0; c2 < 4; c2++) {
      async_copy16(ag + (size_t)c2 * 32 * DIMSZ + k0, &As[buf][(c2 * 32 + wid * 8) * 64]);
      async_copy16(bg + (size_t)c2 * 32 * DIMSZ + k0, &Bs[buf][(c2 * 32 + wid * 8) * 64]);
    }
  };

  stage(0, 0);
  for (int it = 0; it < 16; it++) {
    const int p = it & 1;
    __syncthreads();                    // buf[p] copies drained; buf[1-p] free
    if (it < 15) stage((it + 1) * 64, 1 - p);
#pragma unroll
    for (int kk = 0; kk < 2; kk++) {
      bf16x8 af[4], bfr[4];
#pragma unroll
      for (int r = 0; r < 4; r++) {
        int row = wm * 64 + r * 16 + l16;
        int slot = (kk * 4 + quad) ^ (row & 7);
        af[r] = *(const bf16x8*)(&As[p][0] + row * 64 + slot * 8);
      }
#pragma unroll
      for (int c = 0; c < 4; c++) {
        int row = wn * 64 + c * 16 + l16;
        int slot = (kk * 4 + quad) ^ (row & 7);
        bfr[c] = *(const bf16x8*)(&Bs[p][0] + row * 64 + slot * 8);
      }
#pragma unroll
      for (int r = 0; r < 4; r++)
#pragma unroll
        for (int c = 0; c < 4; c++)
          acc[r][c] = __builtin_amdgcn_mfma_f32_16x16x32_bf16(af[r], bfr[c],
                                                              acc[r][c], 0, 0, 0);
    }
  }
}

// ---------------- QKV projection (grid.z selects q/k/v) ----------------
// q,k: bf16 head-major [b][h][n][d]; v: TRANSPOSED [b][h][d][n]
__global__ __launch_bounds__(256, 2) void gemm_qkv(
    const bf16_t* __restrict__ A,
    const bf16_t* __restrict__ Wt0, const bf16_t* __restrict__ Wt1,
    const bf16_t* __restrict__ Wt2,
    const float* __restrict__ b0, const float* __restrict__ b1,
    const float* __restrict__ b2,
    bf16_t* __restrict__ o0, bf16_t* __restrict__ o1, bf16_t* __restrict__ o2) {
  const bf16_t* Bt; const float* bias; bf16_t* dst;
  if (blockIdx.z == 0)      { Bt = Wt0; bias = b0; dst = o0; }
  else if (blockIdx.z == 1) { Bt = Wt1; bias = b1; dst = o1; }
  else                      { Bt = Wt2; bias = b2; dst = o2; }
  const int m0 = blockIdx.x * 128, n0 = blockIdx.y * 128;
  f32x4 acc[4][4];
  gemm_mainloop(A, Bt, m0, n0, acc);
  const int lane = threadIdx.x & 63, wid = threadIdx.x >> 6;
  const int quad = lane >> 4, l16 = lane & 15;
  const int wm = wid & 1, wn = wid >> 1;
  if (blockIdx.z == 2) {
    // V^T epilogue: [b][h][d][n], vectorized 8B stores (4 consecutive n)
#pragma unroll
    for (int c = 0; c < 4; c++) {
      int col = n0 + wn * 64 + c * 16 + l16;
      float bv = bias[col];
      int hh = col >> 6, dd = col & 63;
#pragma unroll
      for (int r = 0; r < 4; r++) {
        int row = m0 + wm * 64 + r * 16 + quad * 4;
        int bb = row >> 11, nn = row & (SEQ - 1);
        bf16x4 pk;
#pragma unroll
        for (int rr = 0; rr < 4; rr++) pk[rr] = (__bf16)(acc[r][c][rr] + bv);
        *(bf16x4*)(dst + ((size_t)(bb * NHEAD + hh) * DHEAD + dd) * SEQ + nn) = pk;
      }
    }
  } else {
#pragma unroll
    for (int c = 0; c < 4; c++) {
      int col = n0 + wn * 64 + c * 16 + l16;
      float bv = bias[col];
      int hh = col >> 6, dd = col & 63;
#pragma unroll
      for (int r = 0; r < 4; r++)
#pragma unroll
        for (int rr = 0; rr < 4; rr++) {
          int row = m0 + wm * 64 + r * 16 + quad * 4 + rr;
          int bb = row >> 11, nn = row & (SEQ - 1);
          dst[(((size_t)(bb * NHEAD + hh) * SEQ + nn) << 6) + dd] =
              (bf16_t)(acc[r][c][rr] + bv);
        }
    }
  }
}

// ---------------- output projection -> fp32 d_out ----------------
__global__ __launch_bounds__(256, 2) void gemm_out(
    const bf16_t* __restrict__ A, const bf16_t* __restrict__ Bt,
    const float* __restrict__ bias, float* __restrict__ dst) {
  const int m0 = blockIdx.x * 128, n0 = blockIdx.y * 128;
  f32x4 acc[4][4];
  gemm_mainloop(A, Bt, m0, n0, acc);
  const int lane = threadIdx.x & 63, wid = threadIdx.x >> 6;
  const int quad = lane >> 4, l16 = lane & 15;
  const int wm = wid & 1, wn = wid >> 1;
#pragma unroll
  for (int c = 0; c < 4; c++) {
    int col = n0 + wn * 64 + c * 16 + l16;
    float bv = bias[col];
#pragma unroll
    for (int r = 0; r < 4; r++)
#pragma unroll
      for (int rr = 0; rr < 4; rr++) {
        int row = m0 + wm * 64 + r * 16 + quad * 4 + rr;
        dst[(size_t)row * DIMSZ + col] = acc[r][c][rr] + bv;
      }
  }
}

// ---------------- flash attention v3 ----------------
// S^T = K*Q^T, fixed-max softmax, double-buffered K/V with prefetch-after-
// barrier, hoisted LDS fragment addresses. 1 WG = (b, h, 128 q-rows).
__global__ __launch_bounds__(256, 3) void attn_kernel(
    const bf16_t* __restrict__ qh, const bf16_t* __restrict__ kh,
    const bf16_t* __restrict__ vt, bf16_t* __restrict__ ao,
    const float* __restrict__ log_temp) {
  __shared__ __attribute__((aligned(16))) bf16_t Ks[2][64 * 64];
  __shared__ __attribute__((aligned(16))) bf16_t Vs[2][64 * 64];
  __shared__ __attribute__((aligned(16))) bf16_t Ps[4][32 * 64];
  const int tid = threadIdx.x;
  const int wid = tid >> 6, lane = tid & 63;
  const int quad = lane >> 4, l16 = lane & 15;
  const int i0 = blockIdx.x * 128;
  const int h = blockIdx.y, b = blockIdx.z;
  const size_t ho = (size_t)(b * NHEAD + h) * SEQ * DHEAD;
  const bf16_t* Q = qh + ho;
  const float ascale = expf(log_temp[0]) * 1.44269504f;
  const float bshift = 16.0f * 1.44269504f;

  const int irow = i0 + wid * 32;
  bf16x8 qf[2][2];
#pragma unroll
  for (int g = 0; g < 2; g++)
#pragma unroll
    for (int jj = 0; jj < 2; jj++)
      qf[g][jj] = *(const bf16x8*)(Q + (size_t)(irow + g * 16 + l16) * DHEAD +
                                   jj * 32 + quad * 8);

  f32x4 oacc[4][2];
#pragma unroll
  for (int c = 0; c < 4; c++)
#pragma unroll
    for (int g = 0; g < 2; g++) oacc[c][g] = f32x4_zero();
  float lsum[2] = {0.f, 0.f};

  const int srow = lane >> 3;
  const int gch = (lane & 7) ^ srow;
  const bf16_t* kg = kh + ho + (size_t)(wid * 8 + srow) * DHEAD + gch * 8;
  const bf16_t* vg = vt + ho + (size_t)(wid * 8 + srow) * SEQ + gch * 8;
  bf16_t* Pw = Ps[wid];
  const int x7 = l16 & 7;
  const int jdiag_t = blockIdx.x * 2 + (wid >> 1);  // diag j-tile index for wave

  // loop-invariant LDS addresses
  int kvoff[4][2];       // K/V fragment read offsets (row c*16+l16, kk chunk)
#pragma unroll
  for (int c = 0; c < 4; c++)
#pragma unroll
    for (int kk = 0; kk < 2; kk++) {
      int row = c * 16 + l16;
      kvoff[c][kk] = row * 64 + (((kk * 4) + quad) ^ x7) * 8;
    }
  bf16_t* pwa[2][4];     // P write addresses (bf16x4)
#pragma unroll
  for (int g = 0; g < 2; g++)
#pragma unroll
    for (int c = 0; c < 4; c++) {
      int slot = (2 * c + (quad >> 1)) ^ x7;
      pwa[g][c] = Pw + (g * 16 + l16) * 64 + slot * 8 + (quad & 1) * 4;
    }
  const bf16_t* paa[2][2];  // P A-frag read addresses
#pragma unroll
  for (int g = 0; g < 2; g++)
#pragma unroll
    for (int kk = 0; kk < 2; kk++)
      paa[g][kk] = Pw + (g * 16 + l16) * 64 + (((kk * 4) + quad) ^ x7) * 8;

  auto stage = [&](int jt, int buf) {
    const bf16_t* kp = kg + (size_t)jt * 64 * DHEAD;
    const bf16_t* vp = vg + jt * 64;
    bf16_t* kd = &Ks[buf][wid * 8 * 64];
    bf16_t* vd = &Vs[buf][wid * 8 * 64];
    async_copy16(kp, kd);
    async_copy16(kp + 32 * DHEAD, kd + 32 * 64);
    async_copy16(vp, vd);
    async_copy16(vp + 32 * SEQ, vd + 32 * 64);
  };

  stage(0, 0);
  for (int jt = 0; jt < SEQ / 64; jt++) {
    const int p = jt & 1;
    __syncthreads();                    // buf[p] ready; buf[1-p] free
    if (jt + 1 < SEQ / 64) stage(jt + 1, 1 - p);
    const bf16_t* Kp = &Ks[p][0];
    const bf16_t* Vp = &Vs[p][0];

    // S^T(64x32) = K * Q^T : D[j][i], row j = c*16+quad*4+rr, col i = g*16+l16
    f32x4 st[4][2];
#pragma unroll
    for (int c = 0; c < 4; c++) {
      bf16x8 kf0 = *(const bf16x8*)(Kp + kvoff[c][0]);
      bf16x8 kf1 = *(const bf16x8*)(Kp + kvoff[c][1]);
#pragma unroll
      for (int g = 0; g < 2; g++) {
        f32x4 s = f32x4_zero();
        s = __builtin_amdgcn_mfma_f32_16x16x32_bf16(kf0, qf[g][0], s, 0, 0, 0);
        s = __builtin_amdgcn_mfma_f32_16x16x32_bf16(kf1, qf[g][1], s, 0, 0, 0);
        st[c][g] = s;
      }
    }

    // in-lane softmax (fixed max) + bf16 pack + vectorized P write
    const int j0 = jt * 64;
    if (jt == jdiag_t) {
#pragma unroll
      for (int g = 0; g < 2; g++) {
        float ls = 0.f;
        const int ig = irow + g * 16 + l16;
#pragma unroll
        for (int c = 0; c < 4; c++) {
          bf16x4 pk;
#pragma unroll
          for (int rr = 0; rr < 4; rr++) {
            float e = __builtin_amdgcn_exp2f(fmaf(st[c][g][rr], ascale, -bshift));
            if (j0 + c * 16 + quad * 4 + rr == ig) e = 0.f;
            ls += e;
            pk[rr] = (__bf16)e;
          }
          *(bf16x4*)pwa[g][c] = pk;
        }
        lsum[g] += ls;
      }
    } else {
#pragma unroll
      for (int g = 0; g < 2; g++) {
        float ls = 0.f;
#pragma unroll
        for (int c = 0; c < 4; c++) {
          bf16x4 pk;
#pragma unroll
          for (int rr = 0; rr < 4; rr++) {
            float e = __builtin_amdgcn_exp2f(fmaf(st[c][g][rr], ascale, -bshift));
            ls += e;
            pk[rr] = (__bf16)e;
          }
          *(bf16x4*)pwa[g][c] = pk;
        }
        lsum[g] += ls;
      }
    }

    // O(32x64) += P(32x64) @ V
    bf16x8 pa[2][2];
#pragma unroll
    for (int g = 0; g < 2; g++) {
      pa[g][0] = *(const bf16x8*)paa[g][0];
      pa[g][1] = *(const bf16x8*)paa[g][1];
    }
#pragma unroll
    for (int c = 0; c < 4; c++) {
      bf16x8 vb0 = *(const bf16x8*)(Vp + kvoff[c][0]);
      bf16x8 vb1 = *(const bf16x8*)(Vp + kvoff[c][1]);
#pragma unroll
      for (int g = 0; g < 2; g++) {
        oacc[c][g] = __builtin_amdgcn_mfma_f32_16x16x32_bf16(pa[g][0], vb0,
                                                             oacc[c][g], 0, 0, 0);
        oacc[c][g] = __builtin_amdgcn_mfma_f32_16x16x32_bf16(pa[g][1], vb1,
                                                             oacc[c][g], 0, 0, 0);
      }
    }
  }

  // final l reduction (across the 4 quads holding the same q-row)
#pragma unroll
  for (int g = 0; g < 2; g++) {
    lsum[g] += __shfl_xor(lsum[g], 16);
    lsum[g] += __shfl_xor(lsum[g], 32);
  }
  // epilogue: O /= l, write bf16 [b][n][h*64+d]
#pragma unroll
  for (int g = 0; g < 2; g++)
#pragma unroll
    for (int rr = 0; rr < 4; rr++) {
      float lr = __shfl(lsum[g], (lane & 48) | (quad * 4 + rr));
      float inv = 1.f / lr;
      int row = irow + g * 16 + quad * 4 + rr;
#pragma unroll
      for (int c = 0; c < 4; c++) {
        ao[(size_t)(b * SEQ + row) * DIMSZ + h * DHEAD + c * 16 + l16] =
            (bf16_t)(oacc[c][g][rr] * inv);
      }
    }
}

extern "C" void kernel_launch(void* const* d_in, const int* in_sizes, int n_in,
                              void* d_out, int out_size, void* d_ws, size_t ws_size,
                              hipStream_t stream) {
  const float* x  = (const float*)d_in[0];
  const float* Wq = (const float*)d_in[1];
  const float* bq = (const float*)d_in[2];
  const float* Wk = (const float*)d_in[3];
  const float* bk = (const float*)d_in[4];
  const float* Wv = (const float*)d_in[5];
  const float* bv = (const float*)d_in[6];
  const float* Wo = (const float*)d_in[7];
  const float* bo = (const float*)d_in[8];
  const float* lt = (const float*)d_in[9];

  bf16_t* xb  = (bf16_t*)d_ws;                         // 8192*1024
  bf16_t* wtq = xb  + (size_t)MROWS * DIMSZ;           // 1024*1024 each
  bf16_t* wtk = wtq + (size_t)DIMSZ * DIMSZ;
  bf16_t* wtv = wtk + (size_t)DIMSZ * DIMSZ;
  bf16_t* wto = wtv + (size_t)DIMSZ * DIMSZ;
  bf16_t* qh  = wto + (size_t)DIMSZ * DIMSZ;           // 8192*1024 each
  bf16_t* kh  = qh  + (size_t)MROWS * DIMSZ;
  bf16_t* vh  = kh  + (size_t)MROWS * DIMSZ;           // holds V^T [b][h][d][n]
  bf16_t* ao  = xb;                                    // alias (xb dead after QKV)

  cvt_x<<<dim3(MROWS * DIMSZ / 2048), dim3(256), 0, stream>>>(x, xb);
  transpose_w<<<dim3(32, 32, 4), dim3(32, 8), 0, stream>>>(
      Wq, Wk, Wv, Wo, wtq, wtk, wtv, wto);
  gemm_qkv<<<dim3(64, 8, 3), dim3(256), 0, stream>>>(
      xb, wtq, wtk, wtv, bq, bk, bv, qh, kh, vh);
  attn_kernel<<<dim3(16, NHEAD, NB), dim3(256), 0, stream>>>(qh, kh, vh, ao, lt);
  gemm_out<<<dim3(64, 8), dim3(256), 0, stream>>>(ao, wto, bo, (float*)d_out);
}

// Round 4
// 269.595 us; speedup vs baseline: 2.0809x; 1.0370x over previous
//
#include <hip/hip_runtime.h>
#include <cmath>

typedef __bf16 bf16_t;
typedef __attribute__((ext_vector_type(8))) __bf16 bf16x8;
typedef __attribute__((ext_vector_type(4))) __bf16 bf16x4;
typedef __attribute__((ext_vector_type(2))) __bf16 bf16x2;
typedef __attribute__((ext_vector_type(4))) float f32x4;
typedef __attribute__((ext_vector_type(4))) unsigned uint4v;

#define SEQ   2048
#define NHEAD 16
#define DHEAD 64
#define NB    4
#define DIMSZ 1024
#define MROWS 8192

__device__ __forceinline__ void async_copy16(const void* g, void* lds) {
  __builtin_amdgcn_global_load_lds(
      (__attribute__((address_space(1))) void*)(g),
      (__attribute__((address_space(3))) void*)(lds), 16, 0, 0);
}

__device__ __forceinline__ f32x4 f32x4_zero() {
  f32x4 v; v[0] = 0.f; v[1] = 0.f; v[2] = 0.f; v[3] = 0.f; return v;
}

// quad-permute pair (a,b) -> (X,Y) for C-layout -> B-frag transform:
// X = [a@q0, a@q2, b@q0, b@q2], Y = [a@q1, a@q3, b@q1, b@q3]
__device__ __forceinline__ void permlane_xform(unsigned& a, unsigned& b) {
#if __has_builtin(__builtin_amdgcn_permlane32_swap) && __has_builtin(__builtin_amdgcn_permlane16_swap)
  typedef __attribute__((ext_vector_type(2))) unsigned uint2v;
  uint2v r1 = __builtin_amdgcn_permlane32_swap(a, b, false, false);
  uint2v r2 = __builtin_amdgcn_permlane16_swap(r1[0], r1[1], false, false);
  a = r2[0]; b = r2[1];
#else
  asm volatile("v_permlane32_swap_b32 %0, %1\n\t"
               "v_permlane16_swap_b32 %0, %1"
               : "+v"(a), "+v"(b));
#endif
}

__device__ __forceinline__ unsigned pack_bf16(float lo, float hi) {
  bf16x2 t; t[0] = (__bf16)lo; t[1] = (__bf16)hi;
  return __builtin_bit_cast(unsigned, t);
}

// ---------------- x fp32 -> bf16 ----------------
__global__ __launch_bounds__(256) void cvt_x(const float* __restrict__ x,
                                             bf16_t* __restrict__ xb) {
  size_t i = ((size_t)blockIdx.x * 256 + threadIdx.x) * 8;
  float4 f0 = *(const float4*)(x + i);
  float4 f1 = *(const float4*)(x + i + 4);
  bf16x8 o;
  o[0] = (__bf16)f0.x; o[1] = (__bf16)f0.y; o[2] = (__bf16)f0.z; o[3] = (__bf16)f0.w;
  o[4] = (__bf16)f1.x; o[5] = (__bf16)f1.y; o[6] = (__bf16)f1.z; o[7] = (__bf16)f1.w;
  *(bf16x8*)(xb + i) = o;
}

// ---------------- W [k][n] fp32 -> Wt [n][k] bf16 ----------------
__global__ __launch_bounds__(256) void transpose_w(
    const float* __restrict__ W0, const float* __restrict__ W1,
    const float* __restrict__ W2, const float* __restrict__ W3,
    bf16_t* __restrict__ T0, bf16_t* __restrict__ T1,
    bf16_t* __restrict__ T2, bf16_t* __restrict__ T3) {
  const float* W; bf16_t* T;
  switch (blockIdx.z) {
    case 0: W = W0; T = T0; break;
    case 1: W = W1; T = T1; break;
    case 2: W = W2; T = T2; break;
    default: W = W3; T = T3; break;
  }
  __shared__ float t[32][33];
  int tx = threadIdx.x, ty = threadIdx.y;
  int col = blockIdx.x * 32 + tx;
#pragma unroll
  for (int i = 0; i < 4; i++) {
    int row = blockIdx.y * 32 + ty + i * 8;
    t[ty + i * 8][tx] = W[row * DIMSZ + col];
  }
  __syncthreads();
#pragma unroll
  for (int i = 0; i < 4; i++) {
    int n = blockIdx.x * 32 + ty + i * 8;
    int k = blockIdx.y * 32 + tx;
    T[n * DIMSZ + k] = (bf16_t)t[tx][ty + i * 8];
  }
}

// ---------------- shared GEMM mainloop: C(128x128) = A(128xK) * Bt(128xK)^T --
__device__ __forceinline__ void gemm_mainloop(
    const bf16_t* __restrict__ A, const bf16_t* __restrict__ Bt,
    int m0, int n0, f32x4 acc[4][4]) {
  __shared__ __attribute__((aligned(16))) bf16_t As[2][128 * 64];
  __shared__ __attribute__((aligned(16))) bf16_t Bs[2][128 * 64];
  const int tid = threadIdx.x;
  const int wid = tid >> 6, lane = tid & 63;
  const int quad = lane >> 4, l16 = lane & 15;
  const int wm = wid & 1, wn = wid >> 1;
  const int srow = lane >> 3;
  const int gchunk = (lane & 7) ^ srow;
#pragma unroll
  for (int r = 0; r < 4; r++)
#pragma unroll
    for (int c = 0; c < 4; c++) acc[r][c] = f32x4_zero();

  const bf16_t* ag = A + (size_t)(m0 + wid * 8 + srow) * DIMSZ + gchunk * 8;
  const bf16_t* bg = Bt + (size_t)(n0 + wid * 8 + srow) * DIMSZ + gchunk * 8;

  auto stage = [&](int k0, int buf) {
#pragma unroll
    for (int c2 = 0; c2 < 4; c2++) {
      async_copy16(ag + (size_t)c2 * 32 * DIMSZ + k0, &As[buf][(c2 * 32 + wid * 8) * 64]);
      async_copy16(bg + (size_t)c2 * 32 * DIMSZ + k0, &Bs[buf][(c2 * 32 + wid * 8) * 64]);
    }
  };

  stage(0, 0);
  for (int it = 0; it < 16; it++) {
    const int p = it & 1;
    __syncthreads();
    if (it < 15) stage((it + 1) * 64, 1 - p);
#pragma unroll
    for (int kk = 0; kk < 2; kk++) {
      bf16x8 af[4], bfr[4];
#pragma unroll
      for (int r = 0; r < 4; r++) {
        int row = wm * 64 + r * 16 + l16;
        int slot = (kk * 4 + quad) ^ (row & 7);
        af[r] = *(const bf16x8*)(&As[p][0] + row * 64 + slot * 8);
      }
#pragma unroll
      for (int c = 0; c < 4; c++) {
        int row = wn * 64 + c * 16 + l16;
        int slot = (kk * 4 + quad) ^ (row & 7);
        bfr[c] = *(const bf16x8*)(&Bs[p][0] + row * 64 + slot * 8);
      }
#pragma unroll
      for (int r = 0; r < 4; r++)
#pragma unroll
        for (int c = 0; c < 4; c++)
          acc[r][c] = __builtin_amdgcn_mfma_f32_16x16x32_bf16(af[r], bfr[c],
                                                              acc[r][c], 0, 0, 0);
    }
  }
}

// ---------------- QKV projection (grid.z selects q/k/v) ----------------
__global__ __launch_bounds__(256, 2) void gemm_qkv(
    const bf16_t* __restrict__ A,
    const bf16_t* __restrict__ Wt0, const bf16_t* __restrict__ Wt1,
    const bf16_t* __restrict__ Wt2,
    const float* __restrict__ b0, const float* __restrict__ b1,
    const float* __restrict__ b2,
    bf16_t* __restrict__ o0, bf16_t* __restrict__ o1, bf16_t* __restrict__ o2) {
  const bf16_t* Bt; const float* bias; bf16_t* dst;
  if (blockIdx.z == 0)      { Bt = Wt0; bias = b0; dst = o0; }
  else if (blockIdx.z == 1) { Bt = Wt1; bias = b1; dst = o1; }
  else                      { Bt = Wt2; bias = b2; dst = o2; }
  const int m0 = blockIdx.x * 128, n0 = blockIdx.y * 128;
  f32x4 acc[4][4];
  gemm_mainloop(A, Bt, m0, n0, acc);
  const int lane = threadIdx.x & 63, wid = threadIdx.x >> 6;
  const int quad = lane >> 4, l16 = lane & 15;
  const int wm = wid & 1, wn = wid >> 1;
  if (blockIdx.z == 2) {
    // V^T epilogue: [b][h][d][n]
#pragma unroll
    for (int c = 0; c < 4; c++) {
      int col = n0 + wn * 64 + c * 16 + l16;
      float bv = bias[col];
      int hh = col >> 6, dd = col & 63;
#pragma unroll
      for (int r = 0; r < 4; r++) {
        int row = m0 + wm * 64 + r * 16 + quad * 4;
        int bb = row >> 11, nn = row & (SEQ - 1);
        bf16x4 pk;
#pragma unroll
        for (int rr = 0; rr < 4; rr++) pk[rr] = (__bf16)(acc[r][c][rr] + bv);
        *(bf16x4*)(dst + ((size_t)(bb * NHEAD + hh) * DHEAD + dd) * SEQ + nn) = pk;
      }
    }
  } else {
#pragma unroll
    for (int c = 0; c < 4; c++) {
      int col = n0 + wn * 64 + c * 16 + l16;
      float bv = bias[col];
      int hh = col >> 6, dd = col & 63;
#pragma unroll
      for (int r = 0; r < 4; r++)
#pragma unroll
        for (int rr = 0; rr < 4; rr++) {
          int row = m0 + wm * 64 + r * 16 + quad * 4 + rr;
          int bb = row >> 11, nn = row & (SEQ - 1);
          dst[(((size_t)(bb * NHEAD + hh) * SEQ + nn) << 6) + dd] =
              (bf16_t)(acc[r][c][rr] + bv);
        }
    }
  }
}

// ---------------- output projection -> fp32 d_out ----------------
__global__ __launch_bounds__(256, 2) void gemm_out(
    const bf16_t* __restrict__ A, const bf16_t* __restrict__ Bt,
    const float* __restrict__ bias, float* __restrict__ dst) {
  const int m0 = blockIdx.x * 128, n0 = blockIdx.y * 128;
  f32x4 acc[4][4];
  gemm_mainloop(A, Bt, m0, n0, acc);
  const int lane = threadIdx.x & 63, wid = threadIdx.x >> 6;
  const int quad = lane >> 4, l16 = lane & 15;
  const int wm = wid & 1, wn = wid >> 1;
#pragma unroll
  for (int c = 0; c < 4; c++) {
    int col = n0 + wn * 64 + c * 16 + l16;
    float bv = bias[col];
#pragma unroll
    for (int r = 0; r < 4; r++)
#pragma unroll
      for (int rr = 0; rr < 4; rr++) {
        int row = m0 + wm * 64 + r * 16 + quad * 4 + rr;
        dst[(size_t)row * DIMSZ + col] = acc[r][c][rr] + bv;
      }
  }
}

// ---------------- flash attention v4 ----------------
// S^T = K*Q^T (in-lane softmax), fixed-max exp, PV as O^T = V^T * P^T with
// the C-layout -> B-frag transform done in registers via permlane swaps
// (no P LDS round-trip). LDS = K/V dbuf only (32KB) -> 4 blocks/CU.
// XCD swizzle: all 16 i0-blocks of one (b,h) land on one XCD (K+V = 4MB = L2).
__global__ __launch_bounds__(256, 4) void attn_kernel(
    const bf16_t* __restrict__ qh, const bf16_t* __restrict__ kh,
    const bf16_t* __restrict__ vt, bf16_t* __restrict__ ao,
    const float* __restrict__ log_temp) {
  __shared__ __attribute__((aligned(16))) bf16_t Ks[2][64 * 64];
  __shared__ __attribute__((aligned(16))) bf16_t Vs[2][64 * 64];
  const int tid = threadIdx.x;
  const int wid = tid >> 6, lane = tid & 63;
  const int quad = lane >> 4, l16 = lane & 15;
  // swizzled decode: f%8 == hb%8 -> same (b,h) => same XCD
  const int f = blockIdx.x;
  const int hb = f & 63;
  const int h = hb & 15, b = hb >> 4;
  const int i0 = (f >> 6) * 128;
  const size_t ho = (size_t)(b * NHEAD + h) * SEQ * DHEAD;
  const bf16_t* Q = qh + ho;
  const float ascale = expf(log_temp[0]) * 1.44269504f;
  const float bshift = 16.0f * 1.44269504f;

  const int irow = i0 + wid * 32;
  bf16x8 qf[2][2];
#pragma unroll
  for (int g = 0; g < 2; g++)
#pragma unroll
    for (int jj = 0; jj < 2; jj++)
      qf[g][jj] = *(const bf16x8*)(Q + (size_t)(irow + g * 16 + l16) * DHEAD +
                                   jj * 32 + quad * 8);

  f32x4 oaccT[4][2];  // O^T: [d-chunk c][g], D[d=16c+4q+rr][i=16g+l16]
#pragma unroll
  for (int c = 0; c < 4; c++)
#pragma unroll
    for (int g = 0; g < 2; g++) oaccT[c][g] = f32x4_zero();
  float lsum[2] = {0.f, 0.f};

  const int srow = lane >> 3;
  const int gch = (lane & 7) ^ srow;
  const bf16_t* kg = kh + ho + (size_t)(wid * 8 + srow) * DHEAD + gch * 8;
  const bf16_t* vg = vt + ho + (size_t)(wid * 8 + srow) * SEQ + gch * 8;
  const int x7 = l16 & 7;
  const int jdiag_t = (f >> 6) * 2 + (wid >> 1);

  // loop-invariant LDS read offsets (K rows j / V rows d: same pattern)
  int kvoff[4][2];
#pragma unroll
  for (int c = 0; c < 4; c++)
#pragma unroll
    for (int kk = 0; kk < 2; kk++)
      kvoff[c][kk] = (c * 16 + l16) * 64 + (((kk * 4) + quad) ^ x7) * 8;

  auto stage = [&](int jt, int buf) {
    const bf16_t* kp = kg + (size_t)jt * 64 * DHEAD;
    const bf16_t* vp = vg + jt * 64;
    bf16_t* kd = &Ks[buf][wid * 8 * 64];
    bf16_t* vd = &Vs[buf][wid * 8 * 64];
    async_copy16(kp, kd);
    async_copy16(kp + 32 * DHEAD, kd + 32 * 64);
    async_copy16(vp, vd);
    async_copy16(vp + 32 * SEQ, vd + 32 * 64);
  };

  stage(0, 0);
  for (int jt = 0; jt < SEQ / 64; jt++) {
    const int p = jt & 1;
    __syncthreads();
    if (jt + 1 < SEQ / 64) stage(jt + 1, 1 - p);
    const bf16_t* Kp = &Ks[p][0];
    const bf16_t* Vp = &Vs[p][0];

    // S^T(64x32) = K * Q^T : D[j = 16c+4*quad+rr][i = 16g+l16]
    f32x4 st[4][2];
#pragma unroll
    for (int c = 0; c < 4; c++) {
      bf16x8 kf0 = *(const bf16x8*)(Kp + kvoff[c][0]);
      bf16x8 kf1 = *(const bf16x8*)(Kp + kvoff[c][1]);
#pragma unroll
      for (int g = 0; g < 2; g++) {
        f32x4 s = f32x4_zero();
        s = __builtin_amdgcn_mfma_f32_16x16x32_bf16(kf0, qf[g][0], s, 0, 0, 0);
        s = __builtin_amdgcn_mfma_f32_16x16x32_bf16(kf1, qf[g][1], s, 0, 0, 0);
        st[c][g] = s;
      }
    }

    // fixed-max softmax, packed bf16 pairs pkv[g][c][s] = (e_{2s}, e_{2s+1})
    const int j0 = jt * 64;
    unsigned pkv[2][4][2];
    if (jt == jdiag_t) {
#pragma unroll
      for (int g = 0; g < 2; g++) {
        float ls = 0.f;
        const int ig = irow + g * 16 + l16;
#pragma unroll
        for (int c = 0; c < 4; c++) {
          float e[4];
#pragma unroll
          for (int rr = 0; rr < 4; rr++) {
            float v = __builtin_amdgcn_exp2f(fmaf(st[c][g][rr], ascale, -bshift));
            if (j0 + c * 16 + quad * 4 + rr == ig) v = 0.f;
            e[rr] = v;
          }
          ls += (e[0] + e[1]) + (e[2] + e[3]);
          pkv[g][c][0] = pack_bf16(e[0], e[1]);
          pkv[g][c][1] = pack_bf16(e[2], e[3]);
        }
        lsum[g] += ls;
      }
    } else {
#pragma unroll
      for (int g = 0; g < 2; g++) {
        float ls = 0.f;
#pragma unroll
        for (int c = 0; c < 4; c++) {
          float e[4];
#pragma unroll
          for (int rr = 0; rr < 4; rr++)
            e[rr] = __builtin_amdgcn_exp2f(fmaf(st[c][g][rr], ascale, -bshift));
          ls += (e[0] + e[1]) + (e[2] + e[3]);
          pkv[g][c][0] = pack_bf16(e[0], e[1]);
          pkv[g][c][1] = pack_bf16(e[2], e[3]);
        }
        lsum[g] += ls;
      }
    }

    // C-layout -> B-frag via permlane quad-permute: pb[g][kk]
    bf16x8 pb[2][2];
#pragma unroll
    for (int g = 0; g < 2; g++) {
#pragma unroll
      for (int kk = 0; kk < 2; kk++) {
        unsigned a0 = pkv[g][2 * kk][0], b0 = pkv[g][2 * kk + 1][0];
        unsigned a1 = pkv[g][2 * kk][1], b1 = pkv[g][2 * kk + 1][1];
        permlane_xform(a0, b0);
        permlane_xform(a1, b1);
        uint4v u = {a0, a1, b0, b1};   // regs t0..t3
        pb[g][kk] = __builtin_bit_cast(bf16x8, u);
      }
    }

    // O^T(64x32) += V^T(64x64) * P^T(64x32): A = V^T rows (d), B = pb
#pragma unroll
    for (int c = 0; c < 4; c++) {
      bf16x8 va0 = *(const bf16x8*)(Vp + kvoff[c][0]);
      bf16x8 va1 = *(const bf16x8*)(Vp + kvoff[c][1]);
#pragma unroll
      for (int g = 0; g < 2; g++) {
        oaccT[c][g] = __builtin_amdgcn_mfma_f32_16x16x32_bf16(va0, pb[g][0],
                                                              oaccT[c][g], 0, 0, 0);
        oaccT[c][g] = __builtin_amdgcn_mfma_f32_16x16x32_bf16(va1, pb[g][1],
                                                              oaccT[c][g], 0, 0, 0);
      }
    }
  }

  // reduce lsum across quads (all lanes end with the full row sum)
#pragma unroll
  for (int g = 0; g < 2; g++) {
    lsum[g] += __shfl_xor(lsum[g], 16);
    lsum[g] += __shfl_xor(lsum[g], 32);
    lsum[g] = 1.f / lsum[g];
  }
  // epilogue: O^T element (c,g,rr) = O[i = irow+16g+l16][d = 16c+4*quad+rr]
#pragma unroll
  for (int g = 0; g < 2; g++) {
    const int row = irow + g * 16 + l16;
#pragma unroll
    for (int c = 0; c < 4; c++) {
      bf16x4 o;
#pragma unroll
      for (int rr = 0; rr < 4; rr++) o[rr] = (__bf16)(oaccT[c][g][rr] * lsum[g]);
      *(bf16x4*)(ao + (size_t)(b * SEQ + row) * DIMSZ + h * DHEAD + c * 16 +
                 quad * 4) = o;
    }
  }
}

extern "C" void kernel_launch(void* const* d_in, const int* in_sizes, int n_in,
                              void* d_out, int out_size, void* d_ws, size_t ws_size,
                              hipStream_t stream) {
  const float* x  = (const float*)d_in[0];
  const float* Wq = (const float*)d_in[1];
  const float* bq = (const float*)d_in[2];
  const float* Wk = (const float*)d_in[3];
  const float* bk = (const float*)d_in[4];
  const float* Wv = (const float*)d_in[5];
  const float* bv = (const float*)d_in[6];
  const float* Wo = (const float*)d_in[7];
  const float* bo = (const float*)d_in[8];
  const float* lt = (const float*)d_in[9];

  bf16_t* xb  = (bf16_t*)d_ws;                         // 8192*1024
  bf16_t* wtq = xb  + (size_t)MROWS * DIMSZ;           // 1024*1024 each
  bf16_t* wtk = wtq + (size_t)DIMSZ * DIMSZ;
  bf16_t* wtv = wtk + (size_t)DIMSZ * DIMSZ;
  bf16_t* wto = wtv + (size_t)DIMSZ * DIMSZ;
  bf16_t* qh  = wto + (size_t)DIMSZ * DIMSZ;           // 8192*1024 each
  bf16_t* kh  = qh  + (size_t)MROWS * DIMSZ;
  bf16_t* vh  = kh  + (size_t)MROWS * DIMSZ;           // V^T [b][h][d][n]
  bf16_t* ao  = xb;                                    // alias (xb dead after QKV)

  cvt_x<<<dim3(MROWS * DIMSZ / 2048), dim3(256), 0, stream>>>(x, xb);
  transpose_w<<<dim3(32, 32, 4), dim3(32, 8), 0, stream>>>(
      Wq, Wk, Wv, Wo, wtq, wtk, wtv, wto);
  gemm_qkv<<<dim3(64, 8, 3), dim3(256), 0, stream>>>(
      xb, wtq, wtk, wtv, bq, bk, bv, qh, kh, vh);
  attn_kernel<<<dim3(16 * NHEAD * NB), dim3(256), 0, stream>>>(qh, kh, vh, ao, lt);
  gemm_out<<<dim3(64, 8), dim3(256), 0, stream>>>(ao, wto, bo, (float*)d_out);
}

// Round 6
// 258.585 us; speedup vs baseline: 2.1695x; 1.0426x over previous
//
#include <hip/hip_runtime.h>
#include <cmath>

typedef __bf16 bf16_t;
typedef _Float16 f16_t;
typedef __attribute__((ext_vector_type(8))) __bf16 bf16x8;
typedef __attribute__((ext_vector_type(4))) __bf16 bf16x4;
typedef __attribute__((ext_vector_type(8))) _Float16 f16x8;
typedef __attribute__((ext_vector_type(4))) _Float16 f16x4;
typedef __attribute__((ext_vector_type(2))) __fp16 fp16x2n;  // builtin's native type
typedef __attribute__((ext_vector_type(4))) float f32x4;
typedef __attribute__((ext_vector_type(4))) unsigned uint4v;

#define SEQ   2048
#define NHEAD 16
#define DHEAD 64
#define NB    4
#define DIMSZ 1024
#define MROWS 8192

__device__ __forceinline__ void async_copy16(const void* g, void* lds) {
  __builtin_amdgcn_global_load_lds(
      (__attribute__((address_space(1))) void*)(g),
      (__attribute__((address_space(3))) void*)(lds), 16, 0, 0);
}

__device__ __forceinline__ f32x4 f32x4_zero() {
  f32x4 v; v[0] = 0.f; v[1] = 0.f; v[2] = 0.f; v[3] = 0.f; return v;
}

// quad-permute pair (a,b) -> (X,Y) for C-layout -> B-frag transform
__device__ __forceinline__ void permlane_xform(unsigned& a, unsigned& b) {
#if __has_builtin(__builtin_amdgcn_permlane32_swap) && __has_builtin(__builtin_amdgcn_permlane16_swap)
  typedef __attribute__((ext_vector_type(2))) unsigned uint2v;
  uint2v r1 = __builtin_amdgcn_permlane32_swap(a, b, false, false);
  uint2v r2 = __builtin_amdgcn_permlane16_swap(r1[0], r1[1], false, false);
  a = r2[0]; b = r2[1];
#else
  asm volatile("v_permlane32_swap_b32 %0, %1\n\t"
               "v_permlane16_swap_b32 %0, %1"
               : "+v"(a), "+v"(b));
#endif
}

__device__ __forceinline__ unsigned pkrtz(float a, float b) {
  fp16x2n r = __builtin_amdgcn_cvt_pkrtz(a, b);
  return __builtin_bit_cast(unsigned, r);
}

// ---------------- x fp32 -> bf16 ----------------
__global__ __launch_bounds__(256) void cvt_x(const float* __restrict__ x,
                                             bf16_t* __restrict__ xb) {
  size_t i = ((size_t)blockIdx.x * 256 + threadIdx.x) * 8;
  float4 f0 = *(const float4*)(x + i);
  float4 f1 = *(const float4*)(x + i + 4);
  bf16x8 o;
  o[0] = (__bf16)f0.x; o[1] = (__bf16)f0.y; o[2] = (__bf16)f0.z; o[3] = (__bf16)f0.w;
  o[4] = (__bf16)f1.x; o[5] = (__bf16)f1.y; o[6] = (__bf16)f1.z; o[7] = (__bf16)f1.w;
  *(bf16x8*)(xb + i) = o;
}

// ---------------- W [k][n] fp32 -> Wt [n][k] bf16 ----------------
__global__ __launch_bounds__(256) void transpose_w(
    const float* __restrict__ W0, const float* __restrict__ W1,
    const float* __restrict__ W2, const float* __restrict__ W3,
    bf16_t* __restrict__ T0, bf16_t* __restrict__ T1,
    bf16_t* __restrict__ T2, bf16_t* __restrict__ T3) {
  const float* W; bf16_t* T;
  switch (blockIdx.z) {
    case 0: W = W0; T = T0; break;
    case 1: W = W1; T = T1; break;
    case 2: W = W2; T = T2; break;
    default: W = W3; T = T3; break;
  }
  __shared__ float t[32][33];
  int tx = threadIdx.x, ty = threadIdx.y;
  int col = blockIdx.x * 32 + tx;
#pragma unroll
  for (int i = 0; i < 4; i++) {
    int row = blockIdx.y * 32 + ty + i * 8;
    t[ty + i * 8][tx] = W[row * DIMSZ + col];
  }
  __syncthreads();
#pragma unroll
  for (int i = 0; i < 4; i++) {
    int n = blockIdx.x * 32 + ty + i * 8;
    int k = blockIdx.y * 32 + tx;
    T[n * DIMSZ + k] = (bf16_t)t[tx][ty + i * 8];
  }
}

// ---------------- shared GEMM mainloop: C(128x128) = A(128xK) * Bt(128xK)^T --
__device__ __forceinline__ void gemm_mainloop(
    const bf16_t* __restrict__ A, const bf16_t* __restrict__ Bt,
    int m0, int n0, f32x4 acc[4][4]) {
  __shared__ __attribute__((aligned(16))) bf16_t As[2][128 * 64];
  __shared__ __attribute__((aligned(16))) bf16_t Bs[2][128 * 64];
  const int tid = threadIdx.x;
  const int wid = tid >> 6, lane = tid & 63;
  const int quad = lane >> 4, l16 = lane & 15;
  const int wm = wid & 1, wn = wid >> 1;
  const int srow = lane >> 3;
  const int gchunk = (lane & 7) ^ srow;
#pragma unroll
  for (int r = 0; r < 4; r++)
#pragma unroll
    for (int c = 0; c < 4; c++) acc[r][c] = f32x4_zero();

  const bf16_t* ag = A + (size_t)(m0 + wid * 8 + srow) * DIMSZ + gchunk * 8;
  const bf16_t* bg = Bt + (size_t)(n0 + wid * 8 + srow) * DIMSZ + gchunk * 8;

  auto stage = [&](int k0, int buf) {
#pragma unroll
    for (int c2 = 0; c2 < 4; c2++) {
      async_copy16(ag + (size_t)c2 * 32 * DIMSZ + k0, &As[buf][(c2 * 32 + wid * 8) * 64]);
      async_copy16(bg + (size_t)c2 * 32 * DIMSZ + k0, &Bs[buf][(c2 * 32 + wid * 8) * 64]);
    }
  };

  stage(0, 0);
#pragma unroll 2
  for (int it = 0; it < 16; it++) {
    const int p = it & 1;
    __syncthreads();
    if (it < 15) stage((it + 1) * 64, 1 - p);
#pragma unroll
    for (int kk = 0; kk < 2; kk++) {
      bf16x8 af[4], bfr[4];
#pragma unroll
      for (int r = 0; r < 4; r++) {
        int row = wm * 64 + r * 16 + l16;
        int slot = (kk * 4 + quad) ^ (row & 7);
        af[r] = *(const bf16x8*)(&As[p][0] + row * 64 + slot * 8);
      }
#pragma unroll
      for (int c = 0; c < 4; c++) {
        int row = wn * 64 + c * 16 + l16;
        int slot = (kk * 4 + quad) ^ (row & 7);
        bfr[c] = *(const bf16x8*)(&Bs[p][0] + row * 64 + slot * 8);
      }
#pragma unroll
      for (int r = 0; r < 4; r++)
#pragma unroll
        for (int c = 0; c < 4; c++)
          acc[r][c] = __builtin_amdgcn_mfma_f32_16x16x32_bf16(af[r], bfr[c],
                                                              acc[r][c], 0, 0, 0);
    }
  }
}

// ---------------- QKV projection (grid.z selects q/k/v) ----------------
// q,k: f16 head-major [b][h][n][d]; v: f16 TRANSPOSED [b][h][d][n]
__global__ __launch_bounds__(256, 2) void gemm_qkv(
    const bf16_t* __restrict__ A,
    const bf16_t* __restrict__ Wt0, const bf16_t* __restrict__ Wt1,
    const bf16_t* __restrict__ Wt2,
    const float* __restrict__ b0, const float* __restrict__ b1,
    const float* __restrict__ b2,
    f16_t* __restrict__ o0, f16_t* __restrict__ o1, f16_t* __restrict__ o2) {
  const bf16_t* Bt; const float* bias; f16_t* dst;
  if (blockIdx.z == 0)      { Bt = Wt0; bias = b0; dst = o0; }
  else if (blockIdx.z == 1) { Bt = Wt1; bias = b1; dst = o1; }
  else                      { Bt = Wt2; bias = b2; dst = o2; }
  const int m0 = blockIdx.x * 128, n0 = blockIdx.y * 128;
  f32x4 acc[4][4];
  gemm_mainloop(A, Bt, m0, n0, acc);
  const int lane = threadIdx.x & 63, wid = threadIdx.x >> 6;
  const int quad = lane >> 4, l16 = lane & 15;
  const int wm = wid & 1, wn = wid >> 1;
  if (blockIdx.z == 2) {
    // V^T epilogue: [b][h][d][n]
#pragma unroll
    for (int c = 0; c < 4; c++) {
      int col = n0 + wn * 64 + c * 16 + l16;
      float bv = bias[col];
      int hh = col >> 6, dd = col & 63;
#pragma unroll
      for (int r = 0; r < 4; r++) {
        int row = m0 + wm * 64 + r * 16 + quad * 4;
        int bb = row >> 11, nn = row & (SEQ - 1);
        f16x4 pk;
#pragma unroll
        for (int rr = 0; rr < 4; rr++) pk[rr] = (f16_t)(acc[r][c][rr] + bv);
        *(f16x4*)(dst + ((size_t)(bb * NHEAD + hh) * DHEAD + dd) * SEQ + nn) = pk;
      }
    }
  } else {
#pragma unroll
    for (int c = 0; c < 4; c++) {
      int col = n0 + wn * 64 + c * 16 + l16;
      float bv = bias[col];
      int hh = col >> 6, dd = col & 63;
#pragma unroll
      for (int r = 0; r < 4; r++)
#pragma unroll
        for (int rr = 0; rr < 4; rr++) {
          int row = m0 + wm * 64 + r * 16 + quad * 4 + rr;
          int bb = row >> 11, nn = row & (SEQ - 1);
          dst[(((size_t)(bb * NHEAD + hh) * SEQ + nn) << 6) + dd] =
              (f16_t)(acc[r][c][rr] + bv);
        }
    }
  }
}

// ---------------- output projection -> fp32 d_out ----------------
__global__ __launch_bounds__(256, 2) void gemm_out(
    const bf16_t* __restrict__ A, const bf16_t* __restrict__ Bt,
    const float* __restrict__ bias, float* __restrict__ dst) {
  const int m0 = blockIdx.x * 128, n0 = blockIdx.y * 128;
  f32x4 acc[4][4];
  gemm_mainloop(A, Bt, m0, n0, acc);
  const int lane = threadIdx.x & 63, wid = threadIdx.x >> 6;
  const int quad = lane >> 4, l16 = lane & 15;
  const int wm = wid & 1, wn = wid >> 1;
#pragma unroll
  for (int c = 0; c < 4; c++) {
    int col = n0 + wn * 64 + c * 16 + l16;
    float bv = bias[col];
#pragma unroll
    for (int r = 0; r < 4; r++)
#pragma unroll
      for (int rr = 0; rr < 4; rr++) {
        int row = m0 + wm * 64 + r * 16 + quad * 4 + rr;
        dst[(size_t)row * DIMSZ + col] = acc[r][c][rr] + bv;
      }
  }
}

// ---------------- flash attention v5 (f16, MFMA-l, exp2-direct) -------------
// S^T = K*Q^T with Q pre-scaled by temp*log2e -> p = exp2(S') directly.
// P packed f16 via v_cvt_pkrtz; C->B frag via permlane swaps; l accumulated
// by ones-MFMA (no VALU adds, no shuffles). LDS 32KB dbuf, 4 blocks/CU.
__global__ __launch_bounds__(256, 4) void attn_kernel(
    const f16_t* __restrict__ qh, const f16_t* __restrict__ kh,
    const f16_t* __restrict__ vt, bf16_t* __restrict__ ao,
    const float* __restrict__ log_temp) {
  __shared__ __attribute__((aligned(16))) f16_t Ks[2][64 * 64];
  __shared__ __attribute__((aligned(16))) f16_t Vs[2][64 * 64];
  const int tid = threadIdx.x;
  const int wid = tid >> 6, lane = tid & 63;
  const int quad = lane >> 4, l16 = lane & 15;
  // XCD swizzle: f%64 = (b,h) -> all 16 i0-blocks of one (b,h) on one XCD
  const int f = blockIdx.x;
  const int hb = f & 63;
  const int h = hb & 15, b = hb >> 4;
  const int i0 = (f >> 6) * 128;
  const size_t ho = (size_t)(b * NHEAD + h) * SEQ * DHEAD;
  const f16_t* Q = qh + ho;
  const float qscale = expf(log_temp[0]) * 1.44269504f;

  const int irow = i0 + wid * 32;
  f16x8 qf[2][2];
#pragma unroll
  for (int g = 0; g < 2; g++)
#pragma unroll
    for (int jj = 0; jj < 2; jj++) {
      f16x8 raw = *(const f16x8*)(Q + (size_t)(irow + g * 16 + l16) * DHEAD +
                                  jj * 32 + quad * 8);
#pragma unroll
      for (int e = 0; e < 8; e++) qf[g][jj][e] = (f16_t)((float)raw[e] * qscale);
    }
  f16x8 ones;
#pragma unroll
  for (int e = 0; e < 8; e++) ones[e] = (f16_t)1.0f;

  f32x4 oaccT[4][2];  // O^T: D[d=16c+4q+rr][i=16g+l16]
#pragma unroll
  for (int c = 0; c < 4; c++)
#pragma unroll
    for (int g = 0; g < 2; g++) oaccT[c][g] = f32x4_zero();
  f32x4 acc_l[2];     // l via ones-MFMA: col l16 = i
  acc_l[0] = f32x4_zero(); acc_l[1] = f32x4_zero();

  const int srow = lane >> 3;
  const int gch = (lane & 7) ^ srow;
  const f16_t* kg = kh + ho + (size_t)(wid * 8 + srow) * DHEAD + gch * 8;
  const f16_t* vg = vt + ho + (size_t)(wid * 8 + srow) * SEQ + gch * 8;
  const int x7 = l16 & 7;
  const int jdiag_t = (f >> 6) * 2 + (wid >> 1);

  int kvoff[4][2];
#pragma unroll
  for (int c = 0; c < 4; c++)
#pragma unroll
    for (int kk = 0; kk < 2; kk++)
      kvoff[c][kk] = (c * 16 + l16) * 64 + (((kk * 4) + quad) ^ x7) * 8;

  auto stage = [&](int jt, int buf) {
    const f16_t* kp = kg + (size_t)jt * 64 * DHEAD;
    const f16_t* vp = vg + jt * 64;
    f16_t* kd = &Ks[buf][wid * 8 * 64];
    f16_t* vd = &Vs[buf][wid * 8 * 64];
    async_copy16(kp, kd);
    async_copy16(kp + 32 * DHEAD, kd + 32 * 64);
    async_copy16(vp, vd);
    async_copy16(vp + 32 * SEQ, vd + 32 * 64);
  };

  stage(0, 0);
#pragma unroll 2
  for (int jt = 0; jt < SEQ / 64; jt++) {
    const int p = jt & 1;
    __syncthreads();
    if (jt + 1 < SEQ / 64) stage(jt + 1, 1 - p);
    const f16_t* Kp = &Ks[p][0];
    const f16_t* Vp = &Vs[p][0];

    // S'^T(64x32): D[j = 16c+4*quad+rr][i = 16g+l16], already temp*log2e-scaled
    f32x4 st[4][2];
#pragma unroll
    for (int c = 0; c < 4; c++) {
      f16x8 kf0 = *(const f16x8*)(Kp + kvoff[c][0]);
      f16x8 kf1 = *(const f16x8*)(Kp + kvoff[c][1]);
#pragma unroll
      for (int g = 0; g < 2; g++) {
        f32x4 s = f32x4_zero();
        s = __builtin_amdgcn_mfma_f32_16x16x32_f16(kf0, qf[g][0], s, 0, 0, 0);
        s = __builtin_amdgcn_mfma_f32_16x16x32_f16(kf1, qf[g][1], s, 0, 0, 0);
        st[c][g] = s;
      }
    }

    // p = exp2(S') ; diagonal -> 0 ; pack f16 pairs with one pkrtz each
    const int j0 = jt * 64;
    unsigned pkv[2][4][2];
    if (jt == jdiag_t) {
#pragma unroll
      for (int g = 0; g < 2; g++) {
        const int ig = irow + g * 16 + l16;
#pragma unroll
        for (int c = 0; c < 4; c++) {
          float e[4];
#pragma unroll
          for (int rr = 0; rr < 4; rr++) {
            float v = __builtin_amdgcn_exp2f(st[c][g][rr]);
            if (j0 + c * 16 + quad * 4 + rr == ig) v = 0.f;
            e[rr] = v;
          }
          pkv[g][c][0] = pkrtz(e[0], e[1]);
          pkv[g][c][1] = pkrtz(e[2], e[3]);
        }
      }
    } else {
#pragma unroll
      for (int g = 0; g < 2; g++)
#pragma unroll
        for (int c = 0; c < 4; c++) {
          pkv[g][c][0] = pkrtz(__builtin_amdgcn_exp2f(st[c][g][0]),
                               __builtin_amdgcn_exp2f(st[c][g][1]));
          pkv[g][c][1] = pkrtz(__builtin_amdgcn_exp2f(st[c][g][2]),
                               __builtin_amdgcn_exp2f(st[c][g][3]));
        }
    }

    // C-layout -> B-frag via permlane quad-permute
    f16x8 pb[2][2];
#pragma unroll
    for (int g = 0; g < 2; g++)
#pragma unroll
      for (int kk = 0; kk < 2; kk++) {
        unsigned a0 = pkv[g][2 * kk][0], b0 = pkv[g][2 * kk + 1][0];
        unsigned a1 = pkv[g][2 * kk][1], b1 = pkv[g][2 * kk + 1][1];
        permlane_xform(a0, b0);
        permlane_xform(a1, b1);
        uint4v u = {a0, a1, b0, b1};
        pb[g][kk] = __builtin_bit_cast(f16x8, u);
      }

    // l += ones * P^T  (all D rows = column sums = l_i, col = l16 = own i)
#pragma unroll
    for (int g = 0; g < 2; g++) {
      acc_l[g] = __builtin_amdgcn_mfma_f32_16x16x32_f16(ones, pb[g][0], acc_l[g], 0, 0, 0);
      acc_l[g] = __builtin_amdgcn_mfma_f32_16x16x32_f16(ones, pb[g][1], acc_l[g], 0, 0, 0);
    }

    // O^T(64x32) += V^T(64x64) * P^T(64x32)
#pragma unroll
    for (int c = 0; c < 4; c++) {
      f16x8 va0 = *(const f16x8*)(Vp + kvoff[c][0]);
      f16x8 va1 = *(const f16x8*)(Vp + kvoff[c][1]);
#pragma unroll
      for (int g = 0; g < 2; g++) {
        oaccT[c][g] = __builtin_amdgcn_mfma_f32_16x16x32_f16(va0, pb[g][0],
                                                             oaccT[c][g], 0, 0, 0);
        oaccT[c][g] = __builtin_amdgcn_mfma_f32_16x16x32_f16(va1, pb[g][1],
                                                             oaccT[c][g], 0, 0, 0);
      }
    }
  }

  // epilogue: O^T element (c,g,rr) = O[i = irow+16g+l16][d = 16c+4*quad+rr]
  float inv[2];
  inv[0] = 1.f / acc_l[0][0];
  inv[1] = 1.f / acc_l[1][0];
#pragma unroll
  for (int g = 0; g < 2; g++) {
    const int row = irow + g * 16 + l16;
#pragma unroll
    for (int c = 0; c < 4; c++) {
      bf16x4 o;
#pragma unroll
      for (int rr = 0; rr < 4; rr++) o[rr] = (__bf16)(oaccT[c][g][rr] * inv[g]);
      *(bf16x4*)(ao + (size_t)(b * SEQ + row) * DIMSZ + h * DHEAD + c * 16 +
                 quad * 4) = o;
    }
  }
}

extern "C" void kernel_launch(void* const* d_in, const int* in_sizes, int n_in,
                              void* d_out, int out_size, void* d_ws, size_t ws_size,
                              hipStream_t stream) {
  const float* x  = (const float*)d_in[0];
  const float* Wq = (const float*)d_in[1];
  const float* bq = (const float*)d_in[2];
  const float* Wk = (const float*)d_in[3];
  const float* bk = (const float*)d_in[4];
  const float* Wv = (const float*)d_in[5];
  const float* bv = (const float*)d_in[6];
  const float* Wo = (const float*)d_in[7];
  const float* bo = (const float*)d_in[8];
  const float* lt = (const float*)d_in[9];

  bf16_t* xb  = (bf16_t*)d_ws;                         // 8192*1024
  bf16_t* wtq = xb  + (size_t)MROWS * DIMSZ;           // 1024*1024 each
  bf16_t* wtk = wtq + (size_t)DIMSZ * DIMSZ;
  bf16_t* wtv = wtk + (size_t)DIMSZ * DIMSZ;
  bf16_t* wto = wtv + (size_t)DIMSZ * DIMSZ;
  f16_t*  qh  = (f16_t*)(wto + (size_t)DIMSZ * DIMSZ); // 8192*1024 each (f16)
  f16_t*  kh  = qh  + (size_t)MROWS * DIMSZ;
  f16_t*  vh  = kh  + (size_t)MROWS * DIMSZ;           // V^T [b][h][d][n]
  bf16_t* ao  = xb;                                    // alias (xb dead after QKV)

  cvt_x<<<dim3(MROWS * DIMSZ / 2048), dim3(256), 0, stream>>>(x, xb);
  transpose_w<<<dim3(32, 32, 4), dim3(32, 8), 0, stream>>>(
      Wq, Wk, Wv, Wo, wtq, wtk, wtv, wto);
  gemm_qkv<<<dim3(64, 8, 3), dim3(256), 0, stream>>>(
      xb, wtq, wtk, wtv, bq, bk, bv, qh, kh, vh);
  attn_kernel<<<dim3(16 * NHEAD * NB), dim3(256), 0, stream>>>(qh, kh, vh, ao, lt);
  gemm_out<<<dim3(64, 8), dim3(256), 0, stream>>>(ao, wto, bo, (float*)d_out);
}